// Round 1
// baseline (371.081 us; speedup 1.0000x reference)
//
#include <hip/hip_runtime.h>
#include <cstddef>

#define B_ 2
#define T_ 4
#define N_ 1024
#define FIN_ 256
#define H_ 8
#define D_ 128
#define SLOPE_ 0.2f
#define JT_ 32

// ---------------------------------------------------------------------------
// Kernel 1: ht[b,t,head,n,d] = sum_s h[b,t,n,s] * W[s, head*128+d]
// Per (b,t): C[1024x1024] = A[1024x256] @ W[256x1024], scattered into
// (bt, head, n, d) layout so downstream kernels read contiguous D=128 rows.
// grid (16,16,8) = (hk-tiles, n-tiles, bt), block (16,16), 64x64 tile, BK=32.
// ---------------------------------------------------------------------------
__global__ __launch_bounds__(256) void k_gemm_ht(const float* __restrict__ hin,
                                                 const float* __restrict__ W,
                                                 float* __restrict__ ht) {
    __shared__ float As[64][33];   // +1 pad: column reads (stride 33 == 1 mod 32) conflict-free
    __shared__ float Bs[32][64];
    const int bt  = blockIdx.z;
    const int n0  = blockIdx.y * 64;
    const int hk0 = blockIdx.x * 64;
    const int tx  = threadIdx.x, ty = threadIdx.y;
    const int tid = ty * 16 + tx;
    const float* A = hin + (size_t)bt * N_ * FIN_;
    float acc[4][4] = {{0.f, 0.f, 0.f, 0.f}};

    for (int k0 = 0; k0 < FIN_; k0 += 32) {
        // load A tile 64x32 (float4 per thread x2)
        {
            const int row = tid >> 3;         // 0..31
            const int c4  = (tid & 7) * 4;    // 0..28
            #pragma unroll
            for (int p = 0; p < 2; ++p) {
                const float4 v = *(const float4*)(A + (size_t)(n0 + row + p * 32) * FIN_ + k0 + c4);
                As[row + p * 32][c4 + 0] = v.x;
                As[row + p * 32][c4 + 1] = v.y;
                As[row + p * 32][c4 + 2] = v.z;
                As[row + p * 32][c4 + 3] = v.w;
            }
        }
        // load B tile 32x64
        {
            const int rs = tid >> 4;          // 0..15
            const int c4 = (tid & 15) * 4;    // 0..60
            #pragma unroll
            for (int p = 0; p < 2; ++p) {
                const float4 v = *(const float4*)(W + (size_t)(k0 + rs + p * 16) * (H_ * D_) + hk0 + c4);
                *(float4*)&Bs[rs + p * 16][c4] = v;
            }
        }
        __syncthreads();
        #pragma unroll
        for (int k = 0; k < 32; ++k) {
            const float a0 = As[ty * 4 + 0][k];
            const float a1 = As[ty * 4 + 1][k];
            const float a2 = As[ty * 4 + 2][k];
            const float a3 = As[ty * 4 + 3][k];
            const float4 bv = *(const float4*)&Bs[k][tx * 4];
            acc[0][0] += a0 * bv.x; acc[0][1] += a0 * bv.y; acc[0][2] += a0 * bv.z; acc[0][3] += a0 * bv.w;
            acc[1][0] += a1 * bv.x; acc[1][1] += a1 * bv.y; acc[1][2] += a1 * bv.z; acc[1][3] += a1 * bv.w;
            acc[2][0] += a2 * bv.x; acc[2][1] += a2 * bv.y; acc[2][2] += a2 * bv.z; acc[2][3] += a2 * bv.w;
            acc[3][0] += a3 * bv.x; acc[3][1] += a3 * bv.y; acc[3][2] += a3 * bv.z; acc[3][3] += a3 * bv.w;
        }
        __syncthreads();
    }
    // scatter to (bt, head, n, d): hk0 is a multiple of 64 so the whole block
    // is within one head (head = hk0/128, dbase = hk0%128).
    const int head  = hk0 >> 7;
    const int dbase = (hk0 & 127) + tx * 4;
    #pragma unroll
    for (int r = 0; r < 4; ++r) {
        const int n = n0 + ty * 4 + r;
        float4 v; v.x = acc[r][0]; v.y = acc[r][1]; v.z = acc[r][2]; v.w = acc[r][3];
        *(float4*)(ht + ((size_t)(bt * H_ + head) * N_ + n) * D_ + dbase) = v;
    }
}

// ---------------------------------------------------------------------------
// Kernel 2: src[row] = ht_row . a_src[head], tgt[row] = ht_row . a_tgt[head]
// One wave (64 lanes) per row (D=128 -> 2 elems/lane), shuffle reduce.
// row = ((b*T+t)*H + h)*N + n ; head = (row>>10) & 7
// ---------------------------------------------------------------------------
__global__ __launch_bounds__(256) void k_srctgt(const float* __restrict__ ht,
                                                const float* __restrict__ a,
                                                float* __restrict__ src,
                                                float* __restrict__ tgt) {
    const int wid  = threadIdx.x >> 6;
    const int lane = threadIdx.x & 63;
    const int row  = blockIdx.x * 4 + wid;
    const int head = (row >> 10) & 7;
    const float* hr = ht + (size_t)row * D_;
    const float v0 = hr[lane];
    const float v1 = hr[lane + 64];
    const float* ah = a + head * 256;            // a[head][0:128]=src, [128:256]=tgt
    float s = v0 * ah[lane]       + v1 * ah[lane + 64];
    float t = v0 * ah[128 + lane] + v1 * ah[192 + lane];
    #pragma unroll
    for (int off = 32; off > 0; off >>= 1) {
        s += __shfl_down(s, off);
        t += __shfl_down(t, off);
    }
    if (lane == 0) { src[row] = s; tgt[row] = t; }
}

// ---------------------------------------------------------------------------
// Kernel 3: fused mask + softmax + PV, mean over b.
// grid (N/32, T*H), block 256. Block owns 32 rows (i) x full D=128.
// For each b: loop j-tiles of 32: stage ht tile in LDS, compute
// w = adj ? exp(leakyrelu(src_i + tgt_j)) : 0 (no max-shift needed: |e| small),
// accumulate O += w * ht and denom += w; finally O/denom, average over b.
// Compute mapping: tx=tid&31 -> d0=tx*4 ; tyc=tid>>5 -> rows r0=tyc*4 (4x4 tile).
// ---------------------------------------------------------------------------
__global__ __launch_bounds__(256) void k_attn(const float* __restrict__ ht,
                                              const float* __restrict__ src,
                                              const float* __restrict__ tgt,
                                              const int* __restrict__ adj,
                                              float* __restrict__ out) {
    __shared__ float ht_lds[JT_][D_];   // 16 KB
    __shared__ float w_t[JT_][36];      // [jj][row], pad 36 -> aligned float4 reads, clean writes
    __shared__ float dsum[8][33];       // per-jgrp partial denominators
    const int th  = blockIdx.y;         // t*H + h
    const int i0  = blockIdx.x * 32;
    const int tid = threadIdx.x;
    // compute-phase mapping
    const int tx  = tid & 31;  const int d0 = tx * 4;
    const int tyc = tid >> 5;  const int r0 = tyc * 4;
    // w-phase mapping
    const int rlane = tid & 31;
    const int jgrp  = tid >> 5;         // 0..7, each handles 4 j's
    float stash[4][4];

    #pragma unroll
    for (int b = 0; b < B_; ++b) {
        const int bth = b * (T_ * H_) + th;
        const float* htb  = ht  + (size_t)bth * N_ * D_;
        const float* srcb = src + (size_t)bth * N_;
        const float* tgtb = tgt + (size_t)bth * N_;
        float acc[4][4] = {{0.f, 0.f, 0.f, 0.f}};
        float denom = 0.f;
        const float src_r = srcb[i0 + rlane];

        for (int j0 = 0; j0 < N_; j0 += JT_) {
            __syncthreads();   // previous tile's PV reads done before overwrite
            // stage ht tile (32 x 128 fp32 = 16KB): 4 float4 per thread, coalesced
            {
                const float4* g = (const float4*)(htb + (size_t)j0 * D_);
                float4* l = (float4*)&ht_lds[0][0];
                #pragma unroll
                for (int p = 0; p < 4; ++p) l[tid + p * 256] = g[tid + p * 256];
            }
            // scores -> weights for this tile
            {
                const int4   av = *(const int4*)(adj + (size_t)(i0 + rlane) * N_ + j0 + jgrp * 4);
                const float4 tv = *(const float4*)(tgtb + j0 + jgrp * 4);
                float e, wv;
                e = src_r + tv.x; e = (e >= 0.f) ? e : SLOPE_ * e; wv = (av.x > 0) ? __expf(e) : 0.f; denom += wv; w_t[jgrp * 4 + 0][rlane] = wv;
                e = src_r + tv.y; e = (e >= 0.f) ? e : SLOPE_ * e; wv = (av.y > 0) ? __expf(e) : 0.f; denom += wv; w_t[jgrp * 4 + 1][rlane] = wv;
                e = src_r + tv.z; e = (e >= 0.f) ? e : SLOPE_ * e; wv = (av.z > 0) ? __expf(e) : 0.f; denom += wv; w_t[jgrp * 4 + 2][rlane] = wv;
                e = src_r + tv.w; e = (e >= 0.f) ? e : SLOPE_ * e; wv = (av.w > 0) ? __expf(e) : 0.f; denom += wv; w_t[jgrp * 4 + 3][rlane] = wv;
            }
            __syncthreads();
            // PV: 4 rows x 4 d's per thread
            #pragma unroll
            for (int jj = 0; jj < JT_; ++jj) {
                const float4 wv = *(const float4*)&w_t[jj][r0];
                const float4 hv = *(const float4*)&ht_lds[jj][d0];
                acc[0][0] += wv.x * hv.x; acc[0][1] += wv.x * hv.y; acc[0][2] += wv.x * hv.z; acc[0][3] += wv.x * hv.w;
                acc[1][0] += wv.y * hv.x; acc[1][1] += wv.y * hv.y; acc[1][2] += wv.y * hv.z; acc[1][3] += wv.y * hv.w;
                acc[2][0] += wv.z * hv.x; acc[2][1] += wv.z * hv.y; acc[2][2] += wv.z * hv.z; acc[2][3] += wv.z * hv.w;
                acc[3][0] += wv.w * hv.x; acc[3][1] += wv.w * hv.y; acc[3][2] += wv.w * hv.z; acc[3][3] += wv.w * hv.w;
            }
        }
        // reduce denominators across the 8 jgrp partials per row
        __syncthreads();
        dsum[jgrp][rlane] = denom;
        __syncthreads();
        float invd[4];
        #pragma unroll
        for (int r = 0; r < 4; ++r) {
            float s = 0.f;
            #pragma unroll
            for (int q = 0; q < 8; ++q) s += dsum[q][r0 + r];
            invd[r] = 1.0f / s;
        }
        if (b == 0) {
            #pragma unroll
            for (int r = 0; r < 4; ++r)
                #pragma unroll
                for (int c = 0; c < 4; ++c) stash[r][c] = acc[r][c] * invd[r];
        } else {
            #pragma unroll
            for (int r = 0; r < 4; ++r)
                #pragma unroll
                for (int c = 0; c < 4; ++c) stash[r][c] = 0.5f * (stash[r][c] + acc[r][c] * invd[r]);
        }
    }
    // out[t,h,i,d], each element written by exactly one thread
    #pragma unroll
    for (int r = 0; r < 4; ++r) {
        float4 v; v.x = stash[r][0]; v.y = stash[r][1]; v.z = stash[r][2]; v.w = stash[r][3];
        *(float4*)(out + ((size_t)th * N_ + i0 + r0 + r) * D_ + d0) = v;
    }
}

extern "C" void kernel_launch(void* const* d_in, const int* in_sizes, int n_in,
                              void* d_out, int out_size, void* d_ws, size_t ws_size,
                              hipStream_t stream) {
    const float* h   = (const float*)d_in[0];
    const int*   adj = (const int*)d_in[1];
    const float* W   = (const float*)d_in[2];
    const float* a   = (const float*)d_in[3];
    float* out = (float*)d_out;

    // workspace layout: ht (B*T*H*N*D fp32 = 33.5MB) | src | tgt (64K fp32 each)
    float* ht  = (float*)d_ws;
    float* src = ht + (size_t)B_ * T_ * H_ * N_ * D_;
    float* tgt = src + (size_t)B_ * T_ * H_ * N_;

    k_gemm_ht<<<dim3(16, 16, 8), dim3(16, 16), 0, stream>>>(h, W, ht);
    k_srctgt<<<dim3((B_ * T_ * H_ * N_) / 4), dim3(256), 0, stream>>>(ht, a, src, tgt);
    k_attn<<<dim3(N_ / 32, T_ * H_), dim3(256), 0, stream>>>(ht, src, tgt, adj, out);
}

// Round 2
// 164.433 us; speedup vs baseline: 2.2567x; 2.2567x over previous
//
#include <hip/hip_runtime.h>
#include <cstddef>
#include <cstdint>

#define B_ 2
#define T_ 4
#define N_ 1024
#define FIN_ 256
#define H_ 8
#define D_ 128
#define SLOPE_ 0.2f

typedef __attribute__((ext_vector_type(8))) short short8;
typedef __attribute__((ext_vector_type(4))) float f32x4;

__device__ inline unsigned short f2bf(float f) {
    uint32_t u = __float_as_uint(f);
    uint32_t r = (u + 0x7fffu + ((u >> 16) & 1u)) >> 16;   // RNE
    return (unsigned short)r;
}
__device__ inline float bf2f(unsigned short s) {
    return __uint_as_float(((uint32_t)s) << 16);
}

// ---------------------------------------------------------------------------
// Kernel 0: pack adjacency into bitmask. adjbits[i][w] bit k = adj[i][w*32+k]>0
// ---------------------------------------------------------------------------
__global__ __launch_bounds__(256) void k_packadj(const int* __restrict__ adj,
                                                 uint32_t* __restrict__ adjbits) {
    const int w = blockIdx.x * 256 + threadIdx.x;     // 0 .. 32767
    const int i = w >> 5, jw = w & 31;
    const int4* p = (const int4*)(adj + (size_t)i * N_ + jw * 32);
    uint32_t bits = 0;
    #pragma unroll
    for (int q = 0; q < 8; ++q) {
        const int4 v = p[q];
        bits |= (uint32_t)(v.x > 0) << (q * 4 + 0);
        bits |= (uint32_t)(v.y > 0) << (q * 4 + 1);
        bits |= (uint32_t)(v.z > 0) << (q * 4 + 2);
        bits |= (uint32_t)(v.w > 0) << (q * 4 + 3);
    }
    adjbits[w] = bits;
}

// ---------------------------------------------------------------------------
// Kernel 1: fp32 GEMM ht = h @ W, output written as bf16 TRANSPOSED:
// htT[bth][d][n]  (n contiguous) — the layout the MFMA B-fragment wants.
// grid (16,16,8)=(hk,n,bt), block (16,16), 64x64 tile, BK=32.
// Epilogue: register tile -> LDS (transposed) -> coalesced bf16x8 stores.
// ---------------------------------------------------------------------------
__global__ __launch_bounds__(256) void k_gemm_ht(const float* __restrict__ hin,
                                                 const float* __restrict__ W,
                                                 unsigned short* __restrict__ htT) {
    __shared__ float smem[4160];                       // 16640 B, dual-purpose
    float (*As)[33] = (float(*)[33])smem;              // 64x33
    float (*Bs)[64] = (float(*)[64])(smem + 2112);     // 32x64
    float (*Cs)[65] = (float(*)[65])smem;              // 64x65 (epilogue)

    const int bt  = blockIdx.z;
    const int n0  = blockIdx.y * 64;
    const int hk0 = blockIdx.x * 64;
    const int tx  = threadIdx.x, ty = threadIdx.y;
    const int tid = ty * 16 + tx;
    const float* A = hin + (size_t)bt * N_ * FIN_;
    float acc[4][4] = {{0.f, 0.f, 0.f, 0.f}};

    for (int k0 = 0; k0 < FIN_; k0 += 32) {
        {
            const int row = tid >> 3;
            const int c4  = (tid & 7) * 4;
            #pragma unroll
            for (int p = 0; p < 2; ++p) {
                const float4 v = *(const float4*)(A + (size_t)(n0 + row + p * 32) * FIN_ + k0 + c4);
                As[row + p * 32][c4 + 0] = v.x;
                As[row + p * 32][c4 + 1] = v.y;
                As[row + p * 32][c4 + 2] = v.z;
                As[row + p * 32][c4 + 3] = v.w;
            }
        }
        {
            const int rs = tid >> 4;
            const int c4 = (tid & 15) * 4;
            #pragma unroll
            for (int p = 0; p < 2; ++p) {
                const float4 v = *(const float4*)(W + (size_t)(k0 + rs + p * 16) * (H_ * D_) + hk0 + c4);
                *(float4*)&Bs[rs + p * 16][c4] = v;
            }
        }
        __syncthreads();
        #pragma unroll
        for (int k = 0; k < 32; ++k) {
            const float a0 = As[ty * 4 + 0][k];
            const float a1 = As[ty * 4 + 1][k];
            const float a2 = As[ty * 4 + 2][k];
            const float a3 = As[ty * 4 + 3][k];
            const float4 bv = *(const float4*)&Bs[k][tx * 4];
            acc[0][0] += a0 * bv.x; acc[0][1] += a0 * bv.y; acc[0][2] += a0 * bv.z; acc[0][3] += a0 * bv.w;
            acc[1][0] += a1 * bv.x; acc[1][1] += a1 * bv.y; acc[1][2] += a1 * bv.z; acc[1][3] += a1 * bv.w;
            acc[2][0] += a2 * bv.x; acc[2][1] += a2 * bv.y; acc[2][2] += a2 * bv.z; acc[2][3] += a2 * bv.w;
            acc[3][0] += a3 * bv.x; acc[3][1] += a3 * bv.y; acc[3][2] += a3 * bv.z; acc[3][3] += a3 * bv.w;
        }
        __syncthreads();
    }
    // transpose tile through LDS: Cs[hk_local][n_local]
    #pragma unroll
    for (int r = 0; r < 4; ++r)
        #pragma unroll
        for (int c = 0; c < 4; ++c)
            Cs[tx * 4 + c][ty * 4 + r] = acc[r][c];
    __syncthreads();
    {
        const int hk_local = tid >> 2;
        const int nch      = (tid & 3) * 16;
        const int hk   = hk0 + hk_local;
        const int head = hk >> 7;
        const int d    = hk & 127;
        unsigned short ob[16];
        #pragma unroll
        for (int k = 0; k < 16; ++k) ob[k] = f2bf(Cs[hk_local][nch + k]);
        unsigned short* dst = htT + ((size_t)(bt * H_ + head) * D_ + d) * N_ + n0 + nch;
        *(uint4*)(dst)     = *(uint4*)&ob[0];
        *(uint4*)(dst + 8) = *(uint4*)&ob[8];
    }
}

// ---------------------------------------------------------------------------
// Kernel 2: src/tgt projections from htT (bf16).
// One block per bth (64 blocks); thread owns 4 consecutive n; loop d.
// ---------------------------------------------------------------------------
__global__ __launch_bounds__(256) void k_srctgt(const unsigned short* __restrict__ htT,
                                                const float* __restrict__ a,
                                                float* __restrict__ src,
                                                float* __restrict__ tgt) {
    const int bth  = blockIdx.x;
    const int head = bth & 7;
    const int nb   = threadIdx.x * 4;
    const unsigned short* hb = htT + (size_t)bth * D_ * N_;
    const float* ah = a + head * 256;
    float s[4] = {0.f, 0.f, 0.f, 0.f};
    float t[4] = {0.f, 0.f, 0.f, 0.f};
    for (int d = 0; d < D_; ++d) {
        const ushort4 v = *(const ushort4*)(hb + (size_t)d * N_ + nb);
        const float f0 = bf2f(v.x), f1 = bf2f(v.y), f2 = bf2f(v.z), f3 = bf2f(v.w);
        const float as = ah[d], at = ah[128 + d];
        s[0] += as * f0; s[1] += as * f1; s[2] += as * f2; s[3] += as * f3;
        t[0] += at * f0; t[1] += at * f1; t[2] += at * f2; t[3] += at * f3;
    }
    #pragma unroll
    for (int k = 0; k < 4; ++k) {
        src[(size_t)bth * N_ + nb + k] = s[k];
        tgt[(size_t)bth * N_ + nb + k] = t[k];
    }
}

// ---------------------------------------------------------------------------
// Kernel 3: fused mask+softmax+PV via MFMA, mean over b.
// grid (16, 32) = (i-tiles of 64, t*H), block 256 (4 waves, 16 rows each).
// Per 32-j tile: stage htT[128][32] -> LDS (pad 40, 2-way-free), lanes compute
// scores straight into the A-fragment layout, 8 MFMAs accumulate 16x128.
// Denominator = per-lane running sum + shfl_xor(16,32).
// ---------------------------------------------------------------------------
__global__ __launch_bounds__(256) void k_attn(const unsigned short* __restrict__ htT,
                                              const float* __restrict__ src,
                                              const float* __restrict__ tgt,
                                              const uint32_t* __restrict__ adjbits,
                                              float* __restrict__ out) {
    __shared__ __align__(16) short hl[128 * 40];       // 10240 B
    const int th  = blockIdx.y;
    const int i0  = blockIdx.x * 64;
    const int tid = threadIdx.x;
    const int w    = tid >> 6;
    const int lane = tid & 63;
    const int row16 = lane & 15;       // A row / B,C col within 16-tile
    const int kgrp  = lane >> 4;       // 0..3
    const int jrel  = kgrp * 8;
    const int i     = i0 + w * 16 + row16;     // score row this lane owns
    // staging mapping
    const int sd    = tid >> 1;
    const int sjoff = (tid & 1) * 16;

    float stash[8][4];

    #pragma unroll
    for (int b = 0; b < B_; ++b) {
        const int bth = b * (T_ * H_) + th;
        const unsigned short* htTb = htT + (size_t)bth * D_ * N_;
        const float* tgtb = tgt + (size_t)bth * N_;
        const float  src_r = src[(size_t)bth * N_ + i];
        f32x4 acc[8];
        #pragma unroll
        for (int nt = 0; nt < 8; ++nt) acc[nt] = (f32x4){0.f, 0.f, 0.f, 0.f};
        float denom = 0.f;

        for (int j0 = 0; j0 < N_; j0 += 32) {
            __syncthreads();    // prev tile's reads done
            // stage htT[0:128][j0:j0+32] -> hl (16 bf16 per thread)
            {
                const unsigned short* g = htTb + (size_t)sd * N_ + j0 + sjoff;
                const uint4 v0 = *(const uint4*)(g);
                const uint4 v1 = *(const uint4*)(g + 8);
                *(uint4*)&hl[sd * 40 + sjoff]     = v0;
                *(uint4*)&hl[sd * 40 + sjoff + 8] = v1;
            }
            // scores for 8 j's -> A fragment (overlaps staging, no LDS use)
            short8 af;
            {
                const uint32_t adjw = adjbits[(size_t)i * 32 + (j0 >> 5)];
                const float4 tv0 = *(const float4*)(tgtb + j0 + jrel);
                const float4 tv1 = *(const float4*)(tgtb + j0 + jrel + 4);
                float tj[8] = {tv0.x, tv0.y, tv0.z, tv0.w, tv1.x, tv1.y, tv1.z, tv1.w};
                #pragma unroll
                for (int e = 0; e < 8; ++e) {
                    float ev = src_r + tj[e];
                    ev = fmaxf(ev, SLOPE_ * ev);               // leaky-relu (slope<1)
                    const float wv = ((adjw >> (jrel + e)) & 1u) ? __expf(ev) : 0.f;
                    denom += wv;
                    af[e] = (short)f2bf(wv);
                }
            }
            __syncthreads();    // staging visible
            #pragma unroll
            for (int nt = 0; nt < 8; ++nt) {
                const short8 bf = *(const short8*)&hl[(nt * 16 + row16) * 40 + jrel];
                acc[nt] = __builtin_amdgcn_mfma_f32_16x16x32_bf16(af, bf, acc[nt], 0, 0, 0);
            }
        }
        // row denominators: sum the 4 k-groups
        denom += __shfl_xor(denom, 16);
        denom += __shfl_xor(denom, 32);
        const float invd = 1.0f / denom;      // valid for row (lane&15)
        float dr[4];
        #pragma unroll
        for (int reg = 0; reg < 4; ++reg)
            dr[reg] = __shfl(invd, kgrp * 4 + reg);   // C row = kgrp*4+reg
        if (b == 0) {
            #pragma unroll
            for (int nt = 0; nt < 8; ++nt)
                #pragma unroll
                for (int reg = 0; reg < 4; ++reg)
                    stash[nt][reg] = acc[nt][reg] * dr[reg];
        } else {
            #pragma unroll
            for (int nt = 0; nt < 8; ++nt)
                #pragma unroll
                for (int reg = 0; reg < 4; ++reg)
                    stash[nt][reg] = 0.5f * (stash[nt][reg] + acc[nt][reg] * dr[reg]);
        }
    }
    // store: C[row][col]: row = kgrp*4+reg (i), col = nt*16+row16 (d)
    #pragma unroll
    for (int nt = 0; nt < 8; ++nt)
        #pragma unroll
        for (int reg = 0; reg < 4; ++reg) {
            const int irow = i0 + w * 16 + kgrp * 4 + reg;
            const int d    = nt * 16 + row16;
            out[((size_t)th * N_ + irow) * D_ + d] = stash[nt][reg];
        }
}

extern "C" void kernel_launch(void* const* d_in, const int* in_sizes, int n_in,
                              void* d_out, int out_size, void* d_ws, size_t ws_size,
                              hipStream_t stream) {
    const float* h   = (const float*)d_in[0];
    const int*   adj = (const int*)d_in[1];
    const float* W   = (const float*)d_in[2];
    const float* a   = (const float*)d_in[3];
    float* out = (float*)d_out;

    // workspace: htT bf16 (8.4M shorts = 16.8MB) | src | tgt (64K f32) | adjbits
    unsigned short* htT = (unsigned short*)d_ws;
    float* src = (float*)((char*)d_ws + (size_t)B_ * T_ * H_ * D_ * N_ * 2);
    float* tgt = src + (size_t)B_ * T_ * H_ * N_;
    uint32_t* adjbits = (uint32_t*)(tgt + (size_t)B_ * T_ * H_ * N_);

    k_packadj<<<dim3(128), dim3(256), 0, stream>>>(adj, adjbits);
    k_gemm_ht<<<dim3(16, 16, 8), dim3(16, 16), 0, stream>>>(h, W, htT);
    k_srctgt<<<dim3(B_ * T_ * H_), dim3(256), 0, stream>>>(htT, a, src, tgt);
    k_attn<<<dim3(16, 32), dim3(256), 0, stream>>>(htT, src, tgt, adjbits, out);
}